// Round 6
// baseline (8017.716 us; speedup 1.0000x reference)
//
#include <hip/hip_runtime.h>

typedef unsigned int u32;
typedef unsigned long long u64;

#define NB 8
#define NPTS 4096
#define MSEL 2048
#define NCENT (NB*MSEL)
#define KNBR 64
#define FEAT 64
#define FIN 67
#define HH 64
#define FOUT 128
#define CAND_CAP 384

// ---------------------------------------------------------------------------
// Kernel 1: exact FPS. Bit-exact distance/argmax arithmetic (verified round
// 4). Reduction: two-phase native 32-bit LDS atomics, ping-pong pair p=s&1:
//   phase 1: atomicMax(val[p], f32bits(bv))   (positive floats int-ordered)
//   phase 2: holders of the max atomicMin(idx[p], bi) -> first occurrence
// Both order-independent -> replay-deterministic. Pair 1-p is reset between
// the two barriers (nobody touches 1-p there), so no reset race.
// ---------------------------------------------------------------------------
__global__ __launch_bounds__(256) void fps_kernel(const float* __restrict__ pos,
        int* __restrict__ sel, float* __restrict__ pos_out,
        float* __restrict__ batch_out) {
    __shared__ float px[NPTS], py[NPTS], pz[NPTS];
    __shared__ int val[2], idxm[2];
    const int b = blockIdx.x, t = threadIdx.x;
    const float* pb = pos + (long)b * NPTS * 3;

    for (int i = t; i < NPTS; i += 256) {
        px[i] = pb[i*3+0];
        py[i] = pb[i*3+1];
        pz[i] = pb[i*3+2];
    }
    if (t == 0) { val[0] = 0; val[1] = 0; idxm[0] = 0x7fffffff; idxm[1] = 0x7fffffff; }
    __syncthreads();

    float rx[16], ry[16], rz[16], md[16];
    #pragma unroll
    for (int j = 0; j < 16; ++j) {
        int i = t + 256*j;
        rx[j] = px[i]; ry[j] = py[i]; rz[j] = pz[i];
        md[j] = __builtin_inff();
    }

    int cur = 0;
    for (int s = 0; s < MSEL; ++s) {
        const int p = s & 1;
        float cx = px[cur], cy = py[cur], cz = pz[cur];
        if (t == 0) {
            int g = b * MSEL + s;
            sel[g] = cur;
            pos_out[g*3+0] = cx;
            pos_out[g*3+1] = cy;
            pos_out[g*3+2] = cz;
            batch_out[g] = (float)b;
        }
        float bv = -1.0f; int bi = 0;
        #pragma unroll
        for (int j = 0; j < 16; ++j) {
            float dx = __fsub_rn(rx[j], cx);
            float dy = __fsub_rn(ry[j], cy);
            float dz = __fsub_rn(rz[j], cz);
            float d  = __fadd_rn(__fadd_rn(__fmul_rn(dx,dx), __fmul_rn(dy,dy)),
                                 __fmul_rn(dz,dz));
            float m = fminf(md[j], d);
            md[j] = m;
            if (m > bv) { bv = m; bi = t + 256*j; }   // strict >: first occurrence
        }
        const int fb = (int)__float_as_uint(bv);      // bv >= 0 -> int-ordered
        atomicMax(&val[p], fb);
        __syncthreads();                               // B1: all maxes visible
        if (fb == val[p]) atomicMin(&idxm[p], bi);
        if (t == 0) { val[1-p] = 0; idxm[1-p] = 0x7fffffff; }  // reset other pair
        __syncthreads();                               // B2: mins + reset visible
        cur = idxm[p];
    }
}

// ---------------------------------------------------------------------------
// 16-channel f32 FMA against one weight row segment (float4 loads, L1-hot)
// ---------------------------------------------------------------------------
__device__ __forceinline__ void fma16(const float* __restrict__ w, float a,
                                      float acc[16]) {
    const float4* p = (const float4*)w;
    float4 w0 = p[0], w1 = p[1], w2 = p[2], w3 = p[3];
    acc[0]  = fmaf(a, w0.x, acc[0]);  acc[1]  = fmaf(a, w0.y, acc[1]);
    acc[2]  = fmaf(a, w0.z, acc[2]);  acc[3]  = fmaf(a, w0.w, acc[3]);
    acc[4]  = fmaf(a, w1.x, acc[4]);  acc[5]  = fmaf(a, w1.y, acc[5]);
    acc[6]  = fmaf(a, w1.z, acc[6]);  acc[7]  = fmaf(a, w1.w, acc[7]);
    acc[8]  = fmaf(a, w2.x, acc[8]);  acc[9]  = fmaf(a, w2.y, acc[9]);
    acc[10] = fmaf(a, w2.z, acc[10]); acc[11] = fmaf(a, w2.w, acc[11]);
    acc[12] = fmaf(a, w3.x, acc[12]); acc[13] = fmaf(a, w3.y, acc[13]);
    acc[14] = fmaf(a, w3.z, acc[14]); acc[15] = fmaf(a, w3.w, acc[15]);
}

__device__ __forceinline__ void load16(const float* __restrict__ src, float acc[16]) {
    const float4* p = (const float4*)src;
    #pragma unroll
    for (int q = 0; q < 4; ++q) {
        float4 v = p[q];
        acc[4*q+0] = v.x; acc[4*q+1] = v.y; acc[4*q+2] = v.z; acc[4*q+3] = v.w;
    }
}

// ---------------------------------------------------------------------------
// Kernel 2: fused radius + PointNetConv + max-pool, 256 threads/block.
// Byte-identical to round 5 (native int LDS atomics only).
// ---------------------------------------------------------------------------
__global__ __launch_bounds__(256) void conv_kernel(const float* __restrict__ x,
        const float* __restrict__ pos, const int* __restrict__ sel,
        const float* __restrict__ W1, const float* __restrict__ b1,
        const float* __restrict__ W2, const float* __restrict__ b2,
        const float* __restrict__ W3, const float* __restrict__ b3,
        float* __restrict__ xout) {
    __shared__ float feat[64][68];   // features, later reused as h2
    __shared__ float h1s[64][68];
    __shared__ float cdv[CAND_CAP];
    __shared__ int   cixv[CAND_CAP];
    __shared__ int   snbr[KNBR];
    __shared__ int   pooli[FOUT];
    __shared__ int   sc[2];
    const int c = blockIdx.x, t = threadIdx.x;
    const int b = c >> 11;
    const float* pb = pos + (long)b * NPTS * 3;
    const int j0 = sel[c];
    const float qx = pb[j0*3+0], qy = pb[j0*3+1], qz = pb[j0*3+2];
    if (t == 0) { sc[0] = 0; sc[1] = 0; }
    if (t < FOUT) pooli[t] = 0;      // relu >= 0 and cnt >= 1 -> 0 is identity
    __syncthreads();

    // ---- radius gather (bit-exact: _rn ops, numpy sum order)
    const float R2 = (float)(0.15 * 0.15);
    for (int it = 0; it < NPTS/256; ++it) {
        int i = t + 256*it;
        float dx = __fsub_rn(qx, pb[i*3+0]);
        float dy = __fsub_rn(qy, pb[i*3+1]);
        float dz = __fsub_rn(qz, pb[i*3+2]);
        float d2 = __fadd_rn(__fadd_rn(__fmul_rn(dx,dx), __fmul_rn(dy,dy)),
                             __fmul_rn(dz,dz));
        if (d2 <= R2) {
            int slot = atomicAdd(&sc[0], 1);
            if (slot < CAND_CAP) { cdv[slot] = d2; cixv[slot] = i; }
        }
    }
    __syncthreads();
    int C = sc[0]; if (C > CAND_CAP) C = CAND_CAP;
    int cnt;
    if (C <= KNBR) {
        for (int e = t; e < C; e += 256) snbr[e] = cixv[e];
        cnt = C;
    } else {
        // lexicographic (d2, idx) rank-select == stable top_k neighbor SET
        for (int e = t; e < C; e += 256) {
            float de = cdv[e]; int ie = cixv[e];
            int rank = 0;
            for (int f = 0; f < C; ++f) {
                float df = cdv[f]; int jf = cixv[f];
                rank += (df < de || (df == de && jf < ie)) ? 1 : 0;
            }
            if (rank < KNBR) {
                int slot = atomicAdd(&sc[1], 1);
                snbr[slot] = ie;
            }
        }
        cnt = KNBR;
    }
    __syncthreads();

    // ---- stage features: 4 threads per neighbor row, float4
    const int kk = t >> 2, sub = t & 3;
    if (kk < cnt) {
        int j = snbr[kk];
        const float4* xr4 = (const float4*)(x + ((long)b*NPTS + j) * FEAT);
        #pragma unroll
        for (int i = 0; i < 4; ++i) {
            int chunk = sub + 4*i;
            *(float4*)&feat[kk][chunk*4] = xr4[chunk];
        }
        if (sub < 3) {
            float qv = (sub == 0) ? qx : ((sub == 1) ? qy : qz);
            feat[kk][64+sub] = __fsub_rn(pb[j*3+sub], qv);
        }
    }
    __syncthreads();

    const int o0 = (t & 3) * 16;
    float acc[16];

    // ---- layer 1: 67 -> 64, row kk, channels o0..o0+15
    if (kk < cnt) {
        load16(b1 + o0, acc);
        for (int f4 = 0; f4 < 16; ++f4) {
            float4 av = *(const float4*)&feat[kk][f4*4];
            const float* wr = W1 + (long)(f4*4)*HH + o0;
            fma16(wr,        av.x, acc);
            fma16(wr +   HH, av.y, acc);
            fma16(wr + 2*HH, av.z, acc);
            fma16(wr + 3*HH, av.w, acc);
        }
        fma16(W1 + 64L*HH + o0, feat[kk][64], acc);
        fma16(W1 + 65L*HH + o0, feat[kk][65], acc);
        fma16(W1 + 66L*HH + o0, feat[kk][66], acc);
        #pragma unroll
        for (int q = 0; q < 16; ++q) h1s[kk][o0+q] = fmaxf(acc[q], 0.0f);
    }
    __syncthreads();

    // ---- layer 2: 64 -> 64 (h2 overwrites feat; stale rows never read)
    if (kk < cnt) {
        load16(b2 + o0, acc);
        for (int f4 = 0; f4 < 16; ++f4) {
            float4 av = *(const float4*)&h1s[kk][f4*4];
            const float* wr = W2 + (long)(f4*4)*HH + o0;
            fma16(wr,        av.x, acc);
            fma16(wr +   HH, av.y, acc);
            fma16(wr + 2*HH, av.z, acc);
            fma16(wr + 3*HH, av.w, acc);
        }
        #pragma unroll
        for (int q = 0; q < 16; ++q) feat[kk][o0+q] = fmaxf(acc[q], 0.0f);
    }
    __syncthreads();

    // ---- layer 3: 64 -> 128 + fused relu/max-pool.
    // thread = (row k3 in 0..31, channel block o3); rows k3 and k3+32.
    const int o3 = (t & 7) * 16;
    const int k3 = t >> 3;
    float rmax[16];
    #pragma unroll
    for (int q = 0; q < 16; ++q) rmax[q] = 0.0f;
    #pragma unroll
    for (int rr = 0; rr < 2; ++rr) {
        int k = k3 + 32*rr;
        if (k < cnt) {
            load16(b3 + o3, acc);
            for (int f4 = 0; f4 < 16; ++f4) {
                float4 av = *(const float4*)&feat[k][f4*4];
                const float* wr = W3 + (long)(f4*4)*FOUT + o3;
                fma16(wr,          av.x, acc);
                fma16(wr +   FOUT, av.y, acc);
                fma16(wr + 2*FOUT, av.z, acc);
                fma16(wr + 3*FOUT, av.w, acc);
            }
            #pragma unroll
            for (int q = 0; q < 16; ++q)
                rmax[q] = fmaxf(rmax[q], fmaxf(acc[q], 0.0f));
        }
    }
    // relu outputs >= 0 -> int bit pattern is order-preserving
    #pragma unroll
    for (int q = 0; q < 16; ++q)
        atomicMax(&pooli[o3+q], __float_as_int(rmax[q]));
    __syncthreads();
    if (t < FOUT) xout[(long)c*FOUT + t] = __int_as_float(pooli[t]);
}

// ---------------------------------------------------------------------------
extern "C" void kernel_launch(void* const* d_in, const int* in_sizes, int n_in,
                              void* d_out, int out_size, void* d_ws, size_t ws_size,
                              hipStream_t stream) {
    const float* x   = (const float*)d_in[0];
    const float* pos = (const float*)d_in[1];
    // d_in[2] = batch (deterministic, unused)
    const float* W1 = (const float*)d_in[3];
    const float* b1 = (const float*)d_in[4];
    const float* W2 = (const float*)d_in[5];
    const float* b2 = (const float*)d_in[6];
    const float* W3 = (const float*)d_in[7];
    const float* b3 = (const float*)d_in[8];

    float* out       = (float*)d_out;
    float* xout      = out;                          // [16384,128] f32
    float* pos_out   = out + (long)NCENT * FOUT;     // [16384,3]   f32
    float* batch_out = pos_out + (long)NCENT * 3;    // [16384]     f32

    int* sel = (int*)d_ws;                           // 16384 ints

    fps_kernel<<<NB, 256, 0, stream>>>(pos, sel, pos_out, batch_out);
    conv_kernel<<<NCENT, 256, 0, stream>>>(x, pos, sel,
                                           W1, b1, W2, b2, W3, b3, xout);
}

// Round 7
// 2331.076 us; speedup vs baseline: 3.4395x; 3.4395x over previous
//
#include <hip/hip_runtime.h>

typedef unsigned short u16;
typedef unsigned int u32;

#define NB 8
#define NPTS 4096
#define MSEL 2048
#define NCENT (NB*MSEL)
#define KNBR 64
#define FEAT 64
#define FIN 67
#define HH 64
#define FOUT 128
#define CAND_CAP 384

#define KP1 96     // layer-1 K padded to 3x32
#define SA 104     // feat A-buffer row stride (bf16 elems); 52 dwords -> 2-way-free banks
#define S2 72      // h1/h2 row stride; 36 dwords -> 2-way-free banks

typedef __attribute__((ext_vector_type(8))) short short8;
typedef __attribute__((ext_vector_type(4))) float f32x4;

__device__ __forceinline__ float bf2f(u16 u) {
    union { u32 i; float f; } v; v.i = ((u32)u) << 16; return v.f;
}
__device__ __forceinline__ u16 f2bf(float f) {
    union { float f; u32 i; } v; v.f = f;
    u32 x = v.i;
    x += 0x7fffu + ((x >> 16) & 1u);
    return (u16)(x >> 16);
}
// split f32 -> bf16 hi + bf16 lo (a ~= hi + lo to ~2^-17 rel)
__device__ __forceinline__ void splitbf(float a, u16& hi, u16& lo) {
    u16 h = f2bf(a);
    hi = h;
    lo = f2bf(__fsub_rn(a, bf2f(h)));
}

// ---------------------------------------------------------------------------
// DPP wave-64 reductions (VALU-latency cross-lane; result broadcast via
// readlane 63). row_shr 1/2/4/8 -> row max at lane15/31/47/63; row_bcast15
// merges rows 0->1, 2->3; row_bcast31 merges halves -> lane 63 holds all.
// Invalid source lanes keep `old` (=v) with bound_ctrl=false: max(v,v)=v.
// ---------------------------------------------------------------------------
__device__ __forceinline__ int wave_max_i(int v) {
    int u;
    u = __builtin_amdgcn_update_dpp(v, v, 0x111, 0xf, 0xf, false); v = max(v, u);
    u = __builtin_amdgcn_update_dpp(v, v, 0x112, 0xf, 0xf, false); v = max(v, u);
    u = __builtin_amdgcn_update_dpp(v, v, 0x114, 0xf, 0xf, false); v = max(v, u);
    u = __builtin_amdgcn_update_dpp(v, v, 0x118, 0xf, 0xf, false); v = max(v, u);
    u = __builtin_amdgcn_update_dpp(v, v, 0x142, 0xf, 0xf, false); v = max(v, u);
    u = __builtin_amdgcn_update_dpp(v, v, 0x143, 0xf, 0xf, false); v = max(v, u);
    return __builtin_amdgcn_readlane(v, 63);
}
__device__ __forceinline__ int wave_min_i(int v) {
    int u;
    u = __builtin_amdgcn_update_dpp(v, v, 0x111, 0xf, 0xf, false); v = min(v, u);
    u = __builtin_amdgcn_update_dpp(v, v, 0x112, 0xf, 0xf, false); v = min(v, u);
    u = __builtin_amdgcn_update_dpp(v, v, 0x114, 0xf, 0xf, false); v = min(v, u);
    u = __builtin_amdgcn_update_dpp(v, v, 0x118, 0xf, 0xf, false); v = min(v, u);
    u = __builtin_amdgcn_update_dpp(v, v, 0x142, 0xf, 0xf, false); v = min(v, u);
    u = __builtin_amdgcn_update_dpp(v, v, 0x143, 0xf, 0xf, false); v = min(v, u);
    return __builtin_amdgcn_readlane(v, 63);
}

// ---------------------------------------------------------------------------
// Kernel 1: exact FPS. Distance/argmax arithmetic bit-identical to verified
// round-6 (_rn ops, numpy order, max value -> min index). Reduction via DPP
// + one barrier/step (ping-pong slots); winner carries its coords; outputs
// buffered in LDS and written once at the end (no per-step vmcnt drains).
// ---------------------------------------------------------------------------
__global__ __launch_bounds__(256) void fps_kernel(const float* __restrict__ pos,
        int* __restrict__ sel, float* __restrict__ pos_out,
        float* __restrict__ batch_out) {
    __shared__ float px[NPTS], py[NPTS], pz[NPTS];
    __shared__ int hist[MSEL];
    __shared__ int sM[2][4], sI[2][4];
    __shared__ float sX[2][4], sY[2][4], sZ[2][4];
    const int b = blockIdx.x, t = threadIdx.x;
    const int wid = t >> 6;
    const float* pb = pos + (long)b * NPTS * 3;

    for (int i = t; i < NPTS; i += 256) {
        px[i] = pb[i*3+0]; py[i] = pb[i*3+1]; pz[i] = pb[i*3+2];
    }
    __syncthreads();

    float rx[16], ry[16], rz[16], md[16];
    #pragma unroll
    for (int j = 0; j < 16; ++j) {
        int i = t + 256*j;
        rx[j] = px[i]; ry[j] = py[i]; rz[j] = pz[i];
        md[j] = __builtin_inff();
    }

    int cur = 0;
    float cx = px[0], cy = py[0], cz = pz[0];
    for (int s = 0; s < MSEL; ++s) {
        const int p = s & 1;
        if (t == 0) hist[s] = cur;
        float bv = -1.0f; int bi = 0;
        #pragma unroll
        for (int j = 0; j < 16; ++j) {
            float dx = __fsub_rn(rx[j], cx);
            float dy = __fsub_rn(ry[j], cy);
            float dz = __fsub_rn(rz[j], cz);
            float d  = __fadd_rn(__fadd_rn(__fmul_rn(dx,dx), __fmul_rn(dy,dy)),
                                 __fmul_rn(dz,dz));
            float m = fminf(md[j], d);
            md[j] = m;
            if (m > bv) { bv = m; bi = t + 256*j; }   // strict >: first occurrence
        }
        const int fb = (int)__float_as_uint(bv);       // bv >= 0 -> int-ordered
        const int Mw = wave_max_i(fb);
        const int cnd = (fb == Mw) ? bi : 0x7fffffff;
        const int Iw = wave_min_i(cnd);                // wave argmax, min index
        if (t == (Iw & 255)) {                         // owner is in this wave
            int j = Iw >> 8;
            sM[p][wid] = Mw; sI[p][wid] = Iw;
            sX[p][wid] = rx[j]; sY[p][wid] = ry[j]; sZ[p][wid] = rz[j];
        }
        __syncthreads();
        int M = sM[p][0], I = sI[p][0];
        float nx = sX[p][0], ny = sY[p][0], nz = sZ[p][0];
        #pragma unroll
        for (int w = 1; w < 4; ++w) {
            int Mo = sM[p][w], Io = sI[p][w];
            if (Mo > M || (Mo == M && Io < I)) {
                M = Mo; I = Io; nx = sX[p][w]; ny = sY[p][w]; nz = sZ[p][w];
            }
        }
        cur = I; cx = nx; cy = ny; cz = nz;
    }
    __syncthreads();
    for (int g = t; g < MSEL; g += 256) {
        int i = hist[g];
        int o = b * MSEL + g;
        sel[o] = i;
        pos_out[o*3+0] = px[i]; pos_out[o*3+1] = py[i]; pos_out[o*3+2] = pz[i];
        batch_out[o] = (float)b;
    }
}

// ---------------------------------------------------------------------------
// Kernel 1.5: weight pre-transform: W -> W^T, bf16 hi/lo split, K-padded.
// Runs once; conv B-fragments then load 8 contiguous bf16 per lane.
// ---------------------------------------------------------------------------
__global__ __launch_bounds__(256) void wcvt_kernel(const float* __restrict__ W1,
        const float* __restrict__ W2, const float* __restrict__ W3,
        u16* __restrict__ w1h, u16* __restrict__ w1l,
        u16* __restrict__ w2h, u16* __restrict__ w2l,
        u16* __restrict__ w3h, u16* __restrict__ w3l) {
    int t = blockIdx.x * 256 + threadIdx.x;
    if (t < 64*KP1) {
        int n = t / KP1, k = t % KP1;
        u16 h, l; splitbf((k < FIN) ? W1[(long)k*HH + n] : 0.0f, h, l);
        w1h[t] = h; w1l[t] = l;
    }
    if (t < 64*64) {
        int n = t / 64, k = t % 64;
        u16 h, l; splitbf(W2[(long)k*HH + n], h, l);
        w2h[t] = h; w2l[t] = l;
    }
    if (t < 128*64) {
        int n = t / 64, k = t % 64;
        u16 h, l; splitbf(W3[(long)k*FOUT + n], h, l);
        w3h[t] = h; w3l[t] = l;
    }
}

// ---------------------------------------------------------------------------
// Kernel 2: fused radius + PointNetConv + max-pool. Gather/rank-select
// byte-identical to verified round-6. MLP via mfma_f32_16x16x32_bf16 with
// hi/lo split on A and B (hh+hl+lh passes -> ~1e-4 abs error).
// A-frag: A[m=lane&15][k=quad*8+j]; C/D: col=lane&15, row=quad*4+reg.
// ---------------------------------------------------------------------------
__global__ __launch_bounds__(256) void conv_kernel(const float* __restrict__ x,
        const float* __restrict__ pos, const int* __restrict__ sel,
        const u16* __restrict__ w1h, const u16* __restrict__ w1l,
        const u16* __restrict__ w2h, const u16* __restrict__ w2l,
        const u16* __restrict__ w3h, const u16* __restrict__ w3l,
        const float* __restrict__ b1, const float* __restrict__ b2,
        const float* __restrict__ b3, float* __restrict__ xout) {
    __shared__ __align__(16) u16 fAh[64*SA], fAl[64*SA];  // feat A; reused as h2 (stride S2)
    __shared__ __align__(16) u16 h1h[64*S2], h1l[64*S2];
    __shared__ float cdv[CAND_CAP];
    __shared__ int   cixv[CAND_CAP];
    __shared__ int   snbr[KNBR];
    __shared__ float poolw[4][FOUT];
    __shared__ int   sc[2];
    const int c = blockIdx.x, t = threadIdx.x;
    const int b = c >> 11;
    const int lane = t & 63, w = t >> 6;
    const float* pb = pos + (long)b * NPTS * 3;
    const int j0 = sel[c];
    const float qx = pb[j0*3+0], qy = pb[j0*3+1], qz = pb[j0*3+2];
    if (t == 0) { sc[0] = 0; sc[1] = 0; }
    {   // zero A buffers (K pad + invalid rows) before the gather barrier
        u32* z1 = (u32*)fAh; u32* z2 = (u32*)fAl;
        for (int i = t; i < 64*SA/2; i += 256) { z1[i] = 0; z2[i] = 0; }
    }
    __syncthreads();

    // ---- radius gather (bit-exact; verified round 4/6)
    const float R2 = (float)(0.15 * 0.15);
    for (int it = 0; it < NPTS/256; ++it) {
        int i = t + 256*it;
        float dx = __fsub_rn(qx, pb[i*3+0]);
        float dy = __fsub_rn(qy, pb[i*3+1]);
        float dz = __fsub_rn(qz, pb[i*3+2]);
        float d2 = __fadd_rn(__fadd_rn(__fmul_rn(dx,dx), __fmul_rn(dy,dy)),
                             __fmul_rn(dz,dz));
        if (d2 <= R2) {
            int slot = atomicAdd(&sc[0], 1);
            if (slot < CAND_CAP) { cdv[slot] = d2; cixv[slot] = i; }
        }
    }
    __syncthreads();
    int C = sc[0]; if (C > CAND_CAP) C = CAND_CAP;
    int cnt;
    if (C <= KNBR) {
        for (int e = t; e < C; e += 256) snbr[e] = cixv[e];
        cnt = C;
    } else {
        for (int e = t; e < C; e += 256) {
            float de = cdv[e]; int ie = cixv[e];
            int rank = 0;
            for (int f = 0; f < C; ++f) {
                float df = cdv[f]; int jf = cixv[f];
                rank += (df < de || (df == de && jf < ie)) ? 1 : 0;
            }
            if (rank < KNBR) {
                int slot = atomicAdd(&sc[1], 1);
                snbr[slot] = ie;
            }
        }
        cnt = KNBR;
    }
    __syncthreads();

    // ---- stage features as bf16 hi/lo (4 threads per row)
    const int kk = t >> 2, sub = t & 3;
    if (kk < cnt) {
        int j = snbr[kk];
        const float4* xr4 = (const float4*)(x + ((long)b*NPTS + j) * FEAT);
        #pragma unroll
        for (int i = 0; i < 4; ++i) {
            int ci = sub*4 + i;
            float4 v = xr4[ci];
            u16 h0,l0,h1_,l1_,h2_,l2_,h3_,l3_;
            splitbf(v.x, h0, l0); splitbf(v.y, h1_, l1_);
            splitbf(v.z, h2_, l2_); splitbf(v.w, h3_, l3_);
            int o = kk*SA + ci*4;
            fAh[o+0]=h0; fAh[o+1]=h1_; fAh[o+2]=h2_; fAh[o+3]=h3_;
            fAl[o+0]=l0; fAl[o+1]=l1_; fAl[o+2]=l2_; fAl[o+3]=l3_;
        }
        if (sub < 3) {
            float qv = (sub == 0) ? qx : ((sub == 1) ? qy : qz);
            u16 h, l; splitbf(__fsub_rn(pb[j*3+sub], qv), h, l);
            fAh[kk*SA + 64 + sub] = h; fAl[kk*SA + 64 + sub] = l;
        }
    }
    __syncthreads();

    const int mrow = w * 16;
    const int mA = mrow + (lane & 15);
    const int kq = (lane >> 4) * 8;
    const int colc = lane & 15;
    const int rgrp = (lane >> 4) * 4;

    // ---- layer 1: 96(67) -> 64
    short8 a1h[3], a1l[3];
    #pragma unroll
    for (int i = 0; i < 3; ++i) {
        a1h[i] = *(const short8*)&fAh[mA*SA + i*32 + kq];
        a1l[i] = *(const short8*)&fAl[mA*SA + i*32 + kq];
    }
    #pragma unroll
    for (int nc = 0; nc < 4; ++nc) {
        int n = nc*16 + colc;
        float bb = b1[n];
        f32x4 acc = {bb, bb, bb, bb};
        short8 bh[3], bl[3];
        #pragma unroll
        for (int i = 0; i < 3; ++i) {
            bh[i] = *(const short8*)&w1h[n*KP1 + i*32 + kq];
            bl[i] = *(const short8*)&w1l[n*KP1 + i*32 + kq];
        }
        #pragma unroll
        for (int i = 0; i < 3; ++i)
            acc = __builtin_amdgcn_mfma_f32_16x16x32_bf16(a1h[i], bh[i], acc, 0,0,0);
        #pragma unroll
        for (int i = 0; i < 3; ++i)
            acc = __builtin_amdgcn_mfma_f32_16x16x32_bf16(a1h[i], bl[i], acc, 0,0,0);
        #pragma unroll
        for (int i = 0; i < 3; ++i)
            acc = __builtin_amdgcn_mfma_f32_16x16x32_bf16(a1l[i], bh[i], acc, 0,0,0);
        #pragma unroll
        for (int r = 0; r < 4; ++r) {
            u16 h, l; splitbf(fmaxf(acc[r], 0.0f), h, l);
            int m = mrow + rgrp + r;
            h1h[m*S2 + n] = h; h1l[m*S2 + n] = l;
        }
    }
    __syncthreads();

    // ---- layer 2: 64 -> 64 (h2 written into fA buffers, stride S2)
    short8 a2h[2], a2l[2];
    #pragma unroll
    for (int i = 0; i < 2; ++i) {
        a2h[i] = *(const short8*)&h1h[mA*S2 + i*32 + kq];
        a2l[i] = *(const short8*)&h1l[mA*S2 + i*32 + kq];
    }
    #pragma unroll
    for (int nc = 0; nc < 4; ++nc) {
        int n = nc*16 + colc;
        float bb = b2[n];
        f32x4 acc = {bb, bb, bb, bb};
        short8 bh[2], bl[2];
        #pragma unroll
        for (int i = 0; i < 2; ++i) {
            bh[i] = *(const short8*)&w2h[n*64 + i*32 + kq];
            bl[i] = *(const short8*)&w2l[n*64 + i*32 + kq];
        }
        #pragma unroll
        for (int i = 0; i < 2; ++i)
            acc = __builtin_amdgcn_mfma_f32_16x16x32_bf16(a2h[i], bh[i], acc, 0,0,0);
        #pragma unroll
        for (int i = 0; i < 2; ++i)
            acc = __builtin_amdgcn_mfma_f32_16x16x32_bf16(a2h[i], bl[i], acc, 0,0,0);
        #pragma unroll
        for (int i = 0; i < 2; ++i)
            acc = __builtin_amdgcn_mfma_f32_16x16x32_bf16(a2l[i], bh[i], acc, 0,0,0);
        #pragma unroll
        for (int r = 0; r < 4; ++r) {
            u16 h, l; splitbf(fmaxf(acc[r], 0.0f), h, l);
            int m = mrow + rgrp + r;
            fAh[m*S2 + n] = h; fAl[m*S2 + n] = l;
        }
    }
    __syncthreads();

    // ---- layer 3: 64 -> 128 + fused relu + masked max-pool
    short8 a3h[2], a3l[2];
    #pragma unroll
    for (int i = 0; i < 2; ++i) {
        a3h[i] = *(const short8*)&fAh[mA*S2 + i*32 + kq];
        a3l[i] = *(const short8*)&fAl[mA*S2 + i*32 + kq];
    }
    #pragma unroll
    for (int nc = 0; nc < 8; ++nc) {
        int n = nc*16 + colc;
        float bb = b3[n];
        f32x4 acc = {bb, bb, bb, bb};
        short8 bh[2], bl[2];
        #pragma unroll
        for (int i = 0; i < 2; ++i) {
            bh[i] = *(const short8*)&w3h[n*64 + i*32 + kq];
            bl[i] = *(const short8*)&w3l[n*64 + i*32 + kq];
        }
        #pragma unroll
        for (int i = 0; i < 2; ++i)
            acc = __builtin_amdgcn_mfma_f32_16x16x32_bf16(a3h[i], bh[i], acc, 0,0,0);
        #pragma unroll
        for (int i = 0; i < 2; ++i)
            acc = __builtin_amdgcn_mfma_f32_16x16x32_bf16(a3h[i], bl[i], acc, 0,0,0);
        #pragma unroll
        for (int i = 0; i < 2; ++i)
            acc = __builtin_amdgcn_mfma_f32_16x16x32_bf16(a3l[i], bh[i], acc, 0,0,0);
        float v = 0.0f;   // relu >= 0 and cnt >= 1 -> 0 is identity
        #pragma unroll
        for (int r = 0; r < 4; ++r) {
            int m = mrow + rgrp + r;
            float hv = fmaxf(acc[r], 0.0f);
            v = (m < cnt) ? fmaxf(v, hv) : v;
        }
        v = fmaxf(v, __shfl_xor(v, 16, 64));
        v = fmaxf(v, __shfl_xor(v, 32, 64));
        if (lane < 16) poolw[w][nc*16 + lane] = v;
    }
    __syncthreads();
    if (t < FOUT) {
        float v = fmaxf(fmaxf(poolw[0][t], poolw[1][t]),
                        fmaxf(poolw[2][t], poolw[3][t]));
        xout[(long)c*FOUT + t] = v;
    }
}

// ---------------------------------------------------------------------------
extern "C" void kernel_launch(void* const* d_in, const int* in_sizes, int n_in,
                              void* d_out, int out_size, void* d_ws, size_t ws_size,
                              hipStream_t stream) {
    const float* x   = (const float*)d_in[0];
    const float* pos = (const float*)d_in[1];
    // d_in[2] = batch (deterministic, unused)
    const float* W1 = (const float*)d_in[3];
    const float* b1 = (const float*)d_in[4];
    const float* W2 = (const float*)d_in[5];
    const float* b2 = (const float*)d_in[6];
    const float* W3 = (const float*)d_in[7];
    const float* b3 = (const float*)d_in[8];

    float* out       = (float*)d_out;
    float* xout      = out;                          // [16384,128] f32
    float* pos_out   = out + (long)NCENT * FOUT;     // [16384,3]   f32
    float* batch_out = pos_out + (long)NCENT * 3;    // [16384]     f32

    int* sel = (int*)d_ws;                           // 65536 B
    u16* w1h = (u16*)((char*)d_ws + 65536);
    u16* w1l = w1h + 64*KP1;
    u16* w2h = w1l + 64*KP1;
    u16* w2l = w2h + 64*64;
    u16* w3h = w2l + 64*64;
    u16* w3l = w3h + 128*64;                         // end: 139264 B

    wcvt_kernel<<<32, 256, 0, stream>>>(W1, W2, W3, w1h, w1l, w2h, w2l, w3h, w3l);
    fps_kernel<<<NB, 256, 0, stream>>>(pos, sel, pos_out, batch_out);
    conv_kernel<<<NCENT, 256, 0, stream>>>(x, pos, sel, w1h, w1l, w2h, w2l,
                                           w3h, w3l, b1, b2, b3, xout);
}